// Round 1
// baseline (1329.221 us; speedup 1.0000x reference)
//
#include <hip/hip_runtime.h>
#include <math.h>

#define B_ROWS 16384
#define IN_DIM 784
#define OUT_DIM 100
#define NITER 50

#define TB 512          // threads per block (main kernel)
#define RPB 64          // rows per block -> grid 256 = 1 block/CU
#define CPT 13          // cols per thread
#define NCX 8           // col-groups (cx = t & 7)
#define CPAD 104        // NCX*CPT padded col count
#define KDIM 100
#define SST 104         // state row stride (floats)
#define WST 100         // W row stride (floats)
#define LDS_BYTES ((2*CPAD*WST + 3*RPB*SST)*4)   // 163,072 B

__device__ __forceinline__ unsigned enc_f(float f) {
  unsigned u = __float_as_uint(f);
  return (u & 0x80000000u) ? ~u : (u | 0x80000000u);
}
__device__ __forceinline__ float dec_f(unsigned e) {
  unsigned u = (e & 0x80000000u) ? (e ^ 0x80000000u) : ~e;
  return __uint_as_float(u);
}

__global__ void k_init(unsigned* wsu) {
  wsu[0] = 0u;            // running max (encoded)
  wsu[1] = 0xFFFFFFFFu;   // running min (encoded)
}

__global__ void k_minmax(const float4* __restrict__ x4, unsigned* __restrict__ wsu) {
  float mx = -3.4e38f, mn = 3.4e38f;
  const int n4 = (B_ROWS * IN_DIM) / 4;   // exactly divisible
  for (int i = blockIdx.x * blockDim.x + threadIdx.x; i < n4; i += gridDim.x * blockDim.x) {
    float4 v = x4[i];
    mx = fmaxf(mx, fmaxf(fmaxf(v.x, v.y), fmaxf(v.z, v.w)));
    mn = fminf(mn, fminf(fminf(v.x, v.y), fminf(v.z, v.w)));
  }
  #pragma unroll
  for (int o = 32; o; o >>= 1) {
    mx = fmaxf(mx, __shfl_xor(mx, o));
    mn = fminf(mn, __shfl_xor(mn, o));
  }
  __shared__ float smx[8], smn[8];
  int wid = threadIdx.x >> 6;
  if ((threadIdx.x & 63) == 0) { smx[wid] = mx; smn[wid] = mn; }
  __syncthreads();
  if (threadIdx.x == 0) {
    int nw = blockDim.x >> 6;
    for (int w = 1; w < nw; ++w) { mx = fmaxf(mx, smx[w]); mn = fminf(mn, smn[w]); }
    atomicMax(&wsu[0], enc_f(mx));
    atomicMin(&wsu[1], enc_f(mn));
  }
}

// W = offdiag(A) + diag((1-m) - sum_j |offdiag_ij|)
__global__ void k_wbuild(const float* __restrict__ A, float* __restrict__ Wout) {
  int c = threadIdx.x;
  if (c < OUT_DIM) {
    float T = 0.f;
    for (int j = 0; j < OUT_DIM; ++j)
      if (j != c) T += fabsf(A[c * OUT_DIM + j]);
    for (int j = 0; j < OUT_DIM; ++j)
      Wout[c * OUT_DIM + j] = (j == c) ? (0.9f - T) : A[c * OUT_DIM + j];
  }
}

__launch_bounds__(TB, 2)
__global__ void k_main(const float* __restrict__ x, const float* __restrict__ epsp,
                       const float* __restrict__ bvec, const float* __restrict__ Wws,
                       const unsigned* __restrict__ wsu, const float* __restrict__ U,
                       float* __restrict__ out) {
  extern __shared__ float lds[];
  float* Wl  = lds;                       // [CPAD][WST]
  float* AWl = lds + CPAD * WST;          // [CPAD][WST]
  float* Zl  = lds + 2 * CPAD * WST;      // [RPB][SST]
  float* Sl  = Zl + RPB * SST;
  float* Dl  = Sl + RPB * SST;
  // injection staging overlays the (not-yet-needed) state region:
  float* Xx  = Zl;                        // [RPB][17]
  float* Xs  = Xx + RPB * 17;
  float* Xd  = Xs + RPB * 17;
  float* Ut  = Xd + RPB * 17;             // [CPAD][17]
  float* AUt = Ut + CPAD * 17;

  const int t = threadIdx.x;
  const int cx = t & (NCX - 1);
  const int rl = t >> 3;                  // 0..63
  const int r0 = blockIdx.x * RPB;
  const int cbase = cx * CPT;

  // ---- load W, |W| into LDS (rows >= OUT_DIM zeroed) ----
  for (int e = t; e < CPAD * WST; e += TB) {
    float w = (e < OUT_DIM * OUT_DIM) ? Wws[e] : 0.f;   // WST == OUT_DIM
    Wl[e] = w;
    AWl[e] = fabsf(w);
  }

  const float eps  = epsp[0];
  const float xmax = dec_f(wsu[0]);
  const float xmin = dec_f(wsu[1]);

  // ---- injection: u = x@U^T + b ; su = xs@U^T + b ; du = xd@|U|^T ----
  float a_u[CPT], a_su[CPT], a_du[CPT];
  #pragma unroll
  for (int j = 0; j < CPT; ++j) {
    int c = cbase + j;
    float bv = (c < OUT_DIM) ? bvec[c] : 0.f;
    a_u[j] = bv; a_su[j] = bv; a_du[j] = 0.f;
  }

  for (int kb = 0; kb < IN_DIM; kb += 16) {
    __syncthreads();   // protect previous tile's reads
    #pragma unroll
    for (int p = 0; p < 2; ++p) {
      int e = t + p * TB;
      int row = e >> 4, kk = e & 15;
      float xv = x[(r0 + row) * IN_DIM + kb + kk];
      float xh = fminf(xv + eps, xmax);
      float xl = fmaxf(xv - eps, xmin);
      Xx[row * 17 + kk] = xv;
      Xs[row * 17 + kk] = 0.5f * (xh + xl);
      Xd[row * 17 + kk] = 0.5f * (xh - xl);
    }
    #pragma unroll
    for (int p = 0; p < 4; ++p) {
      int e = t + p * TB;
      if (e < CPAD * 16) {
        int cc = e >> 4, kk = e & 15;
        float uv = (cc < OUT_DIM) ? U[cc * IN_DIM + kb + kk] : 0.f;
        Ut[cc * 17 + kk]  = uv;
        AUt[cc * 17 + kk] = fabsf(uv);
      }
    }
    __syncthreads();
    #pragma unroll 4
    for (int kk = 0; kk < 16; ++kk) {
      float xv  = Xx[rl * 17 + kk];
      float xsv = Xs[rl * 17 + kk];
      float xdv = Xd[rl * 17 + kk];
      #pragma unroll
      for (int j = 0; j < CPT; ++j) {
        float uv = Ut[(cbase + j) * 17 + kk];
        float av = AUt[(cbase + j) * 17 + kk];
        a_u[j]  = fmaf(xv,  uv, a_u[j]);
        a_su[j] = fmaf(xsv, uv, a_su[j]);
        a_du[j] = fmaf(xdv, av, a_du[j]);
      }
    }
  }

  // ---- zero states z, s, d ----
  __syncthreads();
  for (int e = t; e < RPB * SST; e += TB) { Zl[e] = 0.f; Sl[e] = 0.f; Dl[e] = 0.f; }
  __syncthreads();

  // ---- 50 iterations ----
  for (int it = 0; it < NITER; ++it) {
    float az[CPT], as_[CPT], ad[CPT];
    #pragma unroll
    for (int j = 0; j < CPT; ++j) { az[j] = a_u[j]; as_[j] = a_su[j]; ad[j] = a_du[j]; }

    const float* zrow = Zl + rl * SST;
    const float* srow = Sl + rl * SST;
    const float* drow = Dl + rl * SST;

    #pragma unroll 2
    for (int k = 0; k < KDIM; k += 4) {
      float4 zv = *(const float4*)(zrow + k);
      float4 sv = *(const float4*)(srow + k);
      float4 dv = *(const float4*)(drow + k);
      #pragma unroll
      for (int j = 0; j < CPT; ++j) {
        float4 wv = *(const float4*)(Wl  + (cbase + j) * WST + k);
        float4 av = *(const float4*)(AWl + (cbase + j) * WST + k);
        az[j]  = fmaf(zv.x, wv.x, az[j]);  az[j]  = fmaf(zv.y, wv.y, az[j]);
        az[j]  = fmaf(zv.z, wv.z, az[j]);  az[j]  = fmaf(zv.w, wv.w, az[j]);
        as_[j] = fmaf(sv.x, wv.x, as_[j]); as_[j] = fmaf(sv.y, wv.y, as_[j]);
        as_[j] = fmaf(sv.z, wv.z, as_[j]); as_[j] = fmaf(sv.w, wv.w, as_[j]);
        ad[j]  = fmaf(dv.x, av.x, ad[j]);  ad[j]  = fmaf(dv.y, av.y, ad[j]);
        ad[j]  = fmaf(dv.z, av.z, ad[j]);  ad[j]  = fmaf(dv.w, av.w, ad[j]);
      }
    }
    __syncthreads();   // all reads done before in-place update
    #pragma unroll
    for (int j = 0; j < CPT; ++j) {
      int c = cbase + j;
      float zo = Zl[rl * SST + c], so = Sl[rl * SST + c], dd = Dl[rl * SST + c];
      float zn = fmaxf(az[j], 0.f);
      float rp = fmaxf(as_[j] + ad[j], 0.f);
      float rm = fmaxf(as_[j] - ad[j], 0.f);
      Zl[rl * SST + c] = 0.5f * zo + 0.5f * zn;
      Sl[rl * SST + c] = 0.5f * so + 0.25f * (rp + rm);
      Dl[rl * SST + c] = 0.5f * dd + 0.25f * (rp - rm);
    }
    __syncthreads();   // writes visible before next iteration's reads
  }

  // ---- store: z, zh = s+d, zl = s-d ----
  const int PL = B_ROWS * OUT_DIM;
  #pragma unroll
  for (int j = 0; j < CPT; ++j) {
    int c = cbase + j;
    if (c < OUT_DIM) {
      int gi = (r0 + rl) * OUT_DIM + c;
      float z = Zl[rl * SST + c], s = Sl[rl * SST + c], d = Dl[rl * SST + c];
      out[gi]          = z;
      out[PL + gi]     = s + d;
      out[2 * PL + gi] = s - d;
    }
  }
}

extern "C" void kernel_launch(void* const* d_in, const int* in_sizes, int n_in,
                              void* d_out, int out_size, void* d_ws, size_t ws_size,
                              hipStream_t stream) {
  const float* x   = (const float*)d_in[0];
  const float* eps = (const float*)d_in[1];
  const float* A   = (const float*)d_in[2];
  const float* U   = (const float*)d_in[3];
  const float* b   = (const float*)d_in[4];
  float* out = (float*)d_out;

  unsigned* wsu = (unsigned*)d_ws;
  float* Wws = (float*)d_ws + 16;   // 100x100 W scratch

  (void)hipFuncSetAttribute((const void*)k_main,
                            hipFuncAttributeMaxDynamicSharedMemorySize, LDS_BYTES);

  k_init<<<1, 1, 0, stream>>>(wsu);
  k_minmax<<<1024, 256, 0, stream>>>((const float4*)x, wsu);
  k_wbuild<<<1, 128, 0, stream>>>(A, Wws);
  k_main<<<B_ROWS / RPB, TB, LDS_BYTES, stream>>>(x, eps, b, Wws, wsu, U, out);
}

// Round 2
// 364.334 us; speedup vs baseline: 3.6484x; 3.6484x over previous
//
#include <hip/hip_runtime.h>
#include <math.h>

#define B_ROWS 16384
#define IN_DIM 784
#define OUT_DIM 100
#define NITER 50

#define TB  512          // 8 waves
#define RPB 64           // rows per block -> grid 256
#define NPAD 112         // 7 n-tiles of 16
#define KPAD 128         // 4 k-chunks of 32

typedef float  f32x4  __attribute__((ext_vector_type(4)));
typedef short  short8 __attribute__((ext_vector_type(8)));
typedef unsigned int uint4v __attribute__((ext_vector_type(4)));

#define MFMA16 __builtin_amdgcn_mfma_f32_16x16x32_bf16

// ---- LDS byte map (dynamic, 139264 B total) ----
#define WH_OFF   0            // W_hi  [112][128] bf16, swizzled
#define WL_OFF   28672        // W_lo
#define ZP_OFF   57344        // z     [64][128] bf16
#define SH_OFF   73728        // s_hi  [64][128]
#define SL_OFF   90112        // s_lo
#define DH_OFF   106496       // d_hi
#define DL_OFF   122880       // d_lo
#define LDS_TOTAL 139264
// injection staging overlays the state region (states not live yet)
#define XB_OFF  57344         // x  tile  [64][40] bf16
#define XS_OFF  62464         // xs tile
#define XD_OFF  67584         // xd tile
#define UB_OFF  73728         // U  tile  [112][40] bf16
#define AU_OFF  82688         // |U| tile

__device__ __forceinline__ unsigned enc_f(float f) {
  unsigned u = __float_as_uint(f);
  return (u & 0x80000000u) ? ~u : (u | 0x80000000u);
}
__device__ __forceinline__ float dec_f(unsigned e) {
  unsigned u = (e & 0x80000000u) ? (e ^ 0x80000000u) : ~e;
  return __uint_as_float(u);
}
__device__ __forceinline__ unsigned short bf16t(float f) {   // truncate to bf16 bits
  return (unsigned short)(__float_as_uint(f) >> 16);
}
// pack hi16(f1):hi16(f0) into one u32 (two bf16 lanes)
__device__ __forceinline__ unsigned pk(float f1, float f0) {
  return __builtin_amdgcn_perm(__float_as_uint(f1), __float_as_uint(f0), 0x07060302u);
}

__global__ void k_init(unsigned* wsu) {
  wsu[0] = 0u;
  wsu[1] = 0xFFFFFFFFu;
}

__global__ void k_minmax(const float4* __restrict__ x4, unsigned* __restrict__ wsu) {
  float mx = -3.4e38f, mn = 3.4e38f;
  const int n4 = (B_ROWS * IN_DIM) / 4;
  for (int i = blockIdx.x * blockDim.x + threadIdx.x; i < n4; i += gridDim.x * blockDim.x) {
    float4 v = x4[i];
    mx = fmaxf(mx, fmaxf(fmaxf(v.x, v.y), fmaxf(v.z, v.w)));
    mn = fminf(mn, fminf(fminf(v.x, v.y), fminf(v.z, v.w)));
  }
  #pragma unroll
  for (int o = 32; o; o >>= 1) {
    mx = fmaxf(mx, __shfl_xor(mx, o));
    mn = fminf(mn, __shfl_xor(mn, o));
  }
  __shared__ float smx[8], smn[8];
  int wid = threadIdx.x >> 6;
  if ((threadIdx.x & 63) == 0) { smx[wid] = mx; smn[wid] = mn; }
  __syncthreads();
  if (threadIdx.x == 0) {
    int nw = blockDim.x >> 6;
    for (int w = 1; w < nw; ++w) { mx = fmaxf(mx, smx[w]); mn = fminf(mn, smn[w]); }
    atomicMax(&wsu[0], enc_f(mx));
    atomicMin(&wsu[1], enc_f(mn));
  }
}

__global__ void k_wbuild(const float* __restrict__ A, float* __restrict__ Wout) {
  int c = threadIdx.x;
  if (c < OUT_DIM) {
    float T = 0.f;
    for (int j = 0; j < OUT_DIM; ++j)
      if (j != c) T += fabsf(A[c * OUT_DIM + j]);
    for (int j = 0; j < OUT_DIM; ++j)
      Wout[c * OUT_DIM + j] = (j == c) ? (0.9f - T) : A[c * OUT_DIM + j];
  }
}

__launch_bounds__(TB, 2)
__global__ void k_main(const float* __restrict__ x, const float* __restrict__ epsp,
                       const float* __restrict__ bvec, const float* __restrict__ Wws,
                       const unsigned* __restrict__ wsu, const float* __restrict__ U,
                       float* __restrict__ out) {
  extern __shared__ char lds[];
  const int t    = threadIdx.x;
  const int lane = t & 63;
  const int w    = t >> 6;          // wave 0..7
  const int g    = lane >> 4;       // lane-group 0..3
  const int q15  = lane & 15;
  const int mt   = w & 3;           // m-tile (16 rows)
  const int nh   = w >> 2;          // n-half
  const int NTW  = nh ? 3 : 4;      // n-tiles for this wave
  const int r0   = blockIdx.x * RPB;
  const int arow = mt * 16 + q15;   // A-fragment row
  const int ncol = nh * 64 + q15;   // base output col (+ q*16)

  // ---- pack W into bf16 hi/lo swizzled planes ----
  for (int e = t; e < NPAD * KPAD; e += TB) {
    int n = e >> 7, k = e & 127;
    float wv = (n < OUT_DIM && k < OUT_DIM) ? Wws[n * OUT_DIM + k] : 0.f;
    unsigned u = __float_as_uint(wv);
    float hif = __uint_as_float(u & 0xffff0000u);
    int byte = n * 256 + ((((k >> 3) ^ (n & 7))) << 4) + (k & 7) * 2;
    *(unsigned short*)(lds + WH_OFF + byte) = (unsigned short)(u >> 16);
    *(unsigned short*)(lds + WL_OFF + byte) = bf16t(wv - hif);
  }

  const float eps  = epsp[0];
  const float xmax = dec_f(wsu[0]);
  const float xmin = dec_f(wsu[1]);

  // ---- injection accumulators (C layout: col = ncol+q*16, rows g*4+r) ----
  f32x4 inj_u[4], inj_s[4], inj_d[4];
  #pragma unroll
  for (int q = 0; q < 4; ++q) {
    int n = ncol + q * 16;
    float bn = (q < NTW && n < OUT_DIM) ? bvec[n] : 0.f;
    inj_u[q] = (f32x4){bn, bn, bn, bn};
    inj_s[q] = (f32x4){bn, bn, bn, bn};
    inj_d[q] = (f32x4){0.f, 0.f, 0.f, 0.f};
  }

  // ---- injection: 25 chunks of K=32 over IN_DIM=784 (pad 800) ----
  for (int kb = 0; kb < 25; ++kb) {
    __syncthreads();
    { // stage x tile [64][32] -> x, xs, xd bf16 planes [64][40]
      int row = t >> 3, k4 = t & 7;
      float4 xv;
      if (kb == 24 && k4 >= 4) xv = make_float4(0.f, 0.f, 0.f, 0.f);
      else xv = *(const float4*)(x + (size_t)(r0 + row) * IN_DIM + kb * 32 + k4 * 4);
      float xh0 = fminf(xv.x + eps, xmax), xl0 = fmaxf(xv.x - eps, xmin);
      float xh1 = fminf(xv.y + eps, xmax), xl1 = fmaxf(xv.y - eps, xmin);
      float xh2 = fminf(xv.z + eps, xmax), xl2 = fmaxf(xv.z - eps, xmin);
      float xh3 = fminf(xv.w + eps, xmax), xl3 = fmaxf(xv.w - eps, xmin);
      int byte = row * 80 + k4 * 8;
      *(uint2*)(lds + XB_OFF + byte) = make_uint2(pk(xv.y, xv.x), pk(xv.w, xv.z));
      *(uint2*)(lds + XS_OFF + byte) =
          make_uint2(pk(0.5f * (xh1 + xl1), 0.5f * (xh0 + xl0)),
                     pk(0.5f * (xh3 + xl3), 0.5f * (xh2 + xl2)));
      *(uint2*)(lds + XD_OFF + byte) =
          make_uint2(pk(0.5f * (xh1 - xl1), 0.5f * (xh0 - xl0)),
                     pk(0.5f * (xh3 - xl3), 0.5f * (xh2 - xl2)));
    }
    // stage U tile [112][32] -> U, |U| bf16 planes [112][40]
    #pragma unroll
    for (int p = 0; p < 2; ++p) {
      int e = t + p * TB;
      if (e < NPAD * 8) {
        int c = e >> 3, k4 = e & 7;
        float4 uv;
        if (c >= OUT_DIM || (kb == 24 && k4 >= 4)) uv = make_float4(0.f, 0.f, 0.f, 0.f);
        else uv = *(const float4*)(U + (size_t)c * IN_DIM + kb * 32 + k4 * 4);
        int byte = c * 80 + k4 * 8;
        *(uint2*)(lds + UB_OFF + byte) = make_uint2(pk(uv.y, uv.x), pk(uv.w, uv.z));
        *(uint2*)(lds + AU_OFF + byte) =
            make_uint2(pk(fabsf(uv.y), fabsf(uv.x)), pk(fabsf(uv.w), fabsf(uv.z)));
      }
    }
    __syncthreads();
    { // MFMA accumulate this chunk
      int sa = arow * 80 + g * 16;
      short8 xa  = *(const short8*)(lds + XB_OFF + sa);
      short8 xsa = *(const short8*)(lds + XS_OFF + sa);
      short8 xda = *(const short8*)(lds + XD_OFF + sa);
      #pragma unroll
      for (int q = 0; q < 4; ++q) if (q < NTW) {
        int sb = (ncol + q * 16) * 80 + g * 16;
        short8 ub = *(const short8*)(lds + UB_OFF + sb);
        short8 ab = *(const short8*)(lds + AU_OFF + sb);
        inj_u[q] = MFMA16(xa,  ub, inj_u[q], 0, 0, 0);
        inj_s[q] = MFMA16(xsa, ub, inj_s[q], 0, 0, 0);
        inj_d[q] = MFMA16(xda, ab, inj_d[q], 0, 0, 0);
      }
    }
  }

  // ---- zero state planes, init fp32 state registers ----
  __syncthreads();
  for (int e = t * 16; e < LDS_TOTAL - ZP_OFF; e += TB * 16)
    *(f32x4*)(lds + ZP_OFF + e) = (f32x4){0.f, 0.f, 0.f, 0.f};
  __syncthreads();

  f32x4 zc[4], sc[4], dc[4];
  #pragma unroll
  for (int q = 0; q < 4; ++q) {
    zc[q] = (f32x4){0.f, 0.f, 0.f, 0.f};
    sc[q] = (f32x4){0.f, 0.f, 0.f, 0.f};
    dc[q] = (f32x4){0.f, 0.f, 0.f, 0.f};
  }

  const int abase = arow * 256;
  const int swl   = q15 & 7;

  // ---- 50 fixed-point iterations ----
  for (int it = 0; it < NITER; ++it) {
    f32x4 az[4], as_[4], ad[4];
    #pragma unroll
    for (int q = 0; q < 4; ++q) { az[q] = inj_u[q]; as_[q] = inj_s[q]; ad[q] = inj_d[q]; }

    #pragma unroll
    for (int kc = 0; kc < 4; ++kc) {
      const int sw = ((kc * 4 + g) ^ swl) << 4;
      const int ao = abase + sw;
      short8 z8  = *(const short8*)(lds + ZP_OFF + ao);
      short8 sh8 = *(const short8*)(lds + SH_OFF + ao);
      short8 sl8 = *(const short8*)(lds + SL_OFF + ao);
      short8 dh8 = *(const short8*)(lds + DH_OFF + ao);
      short8 dl8 = *(const short8*)(lds + DL_OFF + ao);
      #pragma unroll
      for (int q = 0; q < 4; ++q) if (q < NTW) {
        const int bo = (ncol + q * 16) * 256 + sw;
        short8 wh = *(const short8*)(lds + WH_OFF + bo);
        short8 wl = *(const short8*)(lds + WL_OFF + bo);
        uint4v whu  = __builtin_bit_cast(uint4v, wh);
        uint4v awhu = whu & 0x7fff7fffu;                                      // |W_hi|
        uint4v awlu = __builtin_bit_cast(uint4v, wl) ^ (whu & 0x80008000u);   // sign(W_hi)*W_lo
        short8 awh = __builtin_bit_cast(short8, awhu);
        short8 awl = __builtin_bit_cast(short8, awlu);
        az[q]  = MFMA16(z8,  wh,  az[q],  0, 0, 0);
        as_[q] = MFMA16(sh8, wh,  as_[q], 0, 0, 0);
        as_[q] = MFMA16(sh8, wl,  as_[q], 0, 0, 0);
        as_[q] = MFMA16(sl8, wh,  as_[q], 0, 0, 0);
        ad[q]  = MFMA16(dh8, awh, ad[q],  0, 0, 0);
        ad[q]  = MFMA16(dh8, awl, ad[q],  0, 0, 0);
        ad[q]  = MFMA16(dl8, awh, ad[q],  0, 0, 0);
      }
    }

    // update (registers only)
    #pragma unroll
    for (int q = 0; q < 4; ++q) if (q < NTW) {
      #pragma unroll
      for (int c = 0; c < 4; ++c) {
        float zn = fmaxf(az[q][c], 0.f);
        zc[q][c] = 0.5f * zc[q][c] + 0.5f * zn;
        float rp = fmaxf(as_[q][c] + ad[q][c], 0.f);
        float rm = fmaxf(as_[q][c] - ad[q][c], 0.f);
        sc[q][c] = 0.5f * sc[q][c] + 0.25f * (rp + rm);
        dc[q][c] = 0.5f * dc[q][c] + 0.25f * (rp - rm);
      }
    }

    if (it < NITER - 1) {
      __syncthreads();   // all frag reads done
      #pragma unroll
      for (int q = 0; q < 4; ++q) if (q < NTW) {
        const int n = ncol + q * 16;
        const int nslot = n >> 3, nrem = (n & 7) * 2;
        #pragma unroll
        for (int r = 0; r < 4; ++r) {
          const int row = mt * 16 + g * 4 + r;
          const int byte = row * 256 + ((nslot ^ (row & 7)) << 4) + nrem;
          *(unsigned short*)(lds + ZP_OFF + byte) = bf16t(zc[q][r]);
          float sv = sc[q][r];
          unsigned su_ = __float_as_uint(sv);
          *(unsigned short*)(lds + SH_OFF + byte) = (unsigned short)(su_ >> 16);
          *(unsigned short*)(lds + SL_OFF + byte) =
              bf16t(sv - __uint_as_float(su_ & 0xffff0000u));
          float dv = dc[q][r];
          unsigned du_ = __float_as_uint(dv);
          *(unsigned short*)(lds + DH_OFF + byte) = (unsigned short)(du_ >> 16);
          *(unsigned short*)(lds + DL_OFF + byte) =
              bf16t(dv - __uint_as_float(du_ & 0xffff0000u));
        }
      }
      __syncthreads();   // writes visible
    }
  }

  // ---- store out: z / zh=s+d / zl=s-d ----
  const int PL = B_ROWS * OUT_DIM;
  #pragma unroll
  for (int q = 0; q < 4; ++q) if (q < NTW) {
    const int n = ncol + q * 16;
    if (n < OUT_DIM) {
      #pragma unroll
      for (int r = 0; r < 4; ++r) {
        const int row = mt * 16 + g * 4 + r;
        const int gi = (r0 + row) * OUT_DIM + n;
        out[gi]          = zc[q][r];
        out[PL + gi]     = sc[q][r] + dc[q][r];
        out[2 * PL + gi] = sc[q][r] - dc[q][r];
      }
    }
  }
}

extern "C" void kernel_launch(void* const* d_in, const int* in_sizes, int n_in,
                              void* d_out, int out_size, void* d_ws, size_t ws_size,
                              hipStream_t stream) {
  const float* x   = (const float*)d_in[0];
  const float* eps = (const float*)d_in[1];
  const float* A   = (const float*)d_in[2];
  const float* U   = (const float*)d_in[3];
  const float* b   = (const float*)d_in[4];
  float* out = (float*)d_out;

  unsigned* wsu = (unsigned*)d_ws;
  float* Wws = (float*)d_ws + 16;

  (void)hipFuncSetAttribute((const void*)k_main,
                            hipFuncAttributeMaxDynamicSharedMemorySize, LDS_TOTAL);

  k_init<<<1, 1, 0, stream>>>(wsu);
  k_minmax<<<1024, 256, 0, stream>>>((const float4*)x, wsu);
  k_wbuild<<<1, 128, 0, stream>>>(A, Wws);
  k_main<<<B_ROWS / RPB, TB, LDS_TOTAL, stream>>>(x, eps, b, Wws, wsu, U, out);
}